// Round 7
// baseline (135.019 us; speedup 1.0000x reference)
//
#include <hip/hip_runtime.h>
#include <hip/hip_bf16.h>
#include <stdint.h>

#define K_DIM 20000
#define N_DIM 512
#define M_DIM 2048

#define BM 128
#define BN 128
#define BK 32              // 32 bf16 = 64 B per LDS row = 4 x 16B chunks
#define NSTEPS 625         // K_DIM / BK (exact)
#define SPLITS 12          // 64 tiles * 12 = 768 blocks = 3 blocks/CU
#define GRID (64 * SPLITS)
#define GEMM_THREADS 256

typedef __bf16 bf16_t;
typedef bf16_t  bf16x8 __attribute__((ext_vector_type(8)));
typedef float   f32x4  __attribute__((ext_vector_type(4)));
typedef uint32_t u32x2 __attribute__((ext_vector_type(2)));
typedef uint32_t u32x4 __attribute__((ext_vector_type(4)));

__device__ __forceinline__ uint32_t pack_bf16x2(float a, float b) {
  uint32_t ua = (uint32_t)__builtin_bit_cast(uint16_t, (bf16_t)a);
  uint32_t ub = (uint32_t)__builtin_bit_cast(uint16_t, (bf16_t)b);
  return ua | (ub << 16);
}

// async global->LDS, 16B per lane. LDS dest is wave-uniform base + lane*16
// (linear); global src is per-lane (pre-swizzled to match swizzled reads).
__device__ __forceinline__ void gload16(const uint16_t* g, uint16_t* l) {
  __builtin_amdgcn_global_load_lds(
      (const __attribute__((address_space(1))) void*)g,
      (__attribute__((address_space(3))) void*)l, 16, 0, 0);
}

// ---------------------------------------------------------------------------
// Kernel 0: E (K x N fp32, row-major) -> Bt (N x K bf16, row-major)
// ---------------------------------------------------------------------------
__global__ __launch_bounds__(256)
void bt_transpose_kernel(const float* __restrict__ B, uint16_t* __restrict__ Bt) {
  const int kb = blockIdx.x;      // 0..624
  const int nb = blockIdx.y;      // 0..7
  const int t  = threadIdx.x;
  const int rn = t >> 2;          // 0..63 local n
  const int kc = t & 3;           // 0..3  (8 k each)
  const int n  = nb * 64 + rn;
  const int kk = kb * 32 + kc * 8;

  float v[8];
#pragma unroll
  for (int j = 0; j < 8; ++j)
    v[j] = B[(size_t)(kk + j) * N_DIM + n];

  u32x4 q;
#pragma unroll
  for (int j = 0; j < 4; ++j)
    q[j] = pack_bf16x2(v[2 * j], v[2 * j + 1]);

  *reinterpret_cast<u32x4*>(&Bt[(size_t)n * K_DIM + kk]) = q;
}

// ---------------------------------------------------------------------------
// Kernel 1: out[m][n] = bias[n]   (accumulation target for split-K atomics)
// ---------------------------------------------------------------------------
__global__ __launch_bounds__(256)
void init_out_kernel(const float* __restrict__ bias, float* __restrict__ out) {
  const int i = blockIdx.x * 256 + threadIdx.x;
  out[i] = bias[i & (N_DIM - 1)];
}

// ---------------------------------------------------------------------------
// Kernel 2: split-K bf16 MFMA GEMM, 128x128 tile, 4 waves (2x2), BK=32.
// 2-deep pipeline on BOTH operands, unroll-by-2 for static reg sets:
//   step i: gload B(i+2) -> Bl[(i+2)&3]; load A(i+2) -> r[i&1];
//           frag-read Al[i&1], Bl[i&3]; 16 MFMA;
//           pack A(i+1) from r[(i+1)&1] -> Al[(i+1)&1];   (compiler's wait
//             for A(i+1) also retires B(i+1), issued earlier -- FIFO)
//           s_waitcnt vmcnt(6) lgkmcnt(0); s_barrier
//             (keeps B(i+2)x2 + A(i+2)x4 in flight across the barrier)
// No register copies: rA/rB alternate by parity (rule #20).
// LDS = 2x8 KB (A) + 4x8 KB (B ring) = 48 KB -> 3 blocks/CU.
// ---------------------------------------------------------------------------
__global__ __launch_bounds__(GEMM_THREADS)
void gemm_split_kernel(const float* __restrict__ X,
                       const uint16_t* __restrict__ Bt,
                       float* __restrict__ out) {
  __shared__ __align__(16) uint16_t Al[2][BM * 32];   // 8 KB each
  __shared__ __align__(16) uint16_t Bl[4][BN * 32];   // 8 KB each (ring of 4)

  // XCD-chunk swizzle (bijective, GRID % 8 == 0): contiguous logical range
  // per XCD; 4 nt-blocks of one (mt,s) x-slice + 16 mt-blocks of one (s,nt)
  // Bt slice co-locate. (R6: FETCH 165->122 MB.)
  const int phys = blockIdx.x;
  const int bid  = (phys & 7) * (GRID / 8) + (phys >> 3);
  const int mt    = bid & 15;         // m-tile 0..15
  const int chunk = bid >> 4;         // 0..(4*SPLITS-1)
  const int nt    = chunk & 3;        // n-tile 0..3
  const int s     = chunk >> 2;       // K-split 0..SPLITS-1
  const int m0 = mt * BM;
  const int n0 = nt * BN;
  const int step0 = (s * NSTEPS) / SPLITS;
  const int step1 = ((s + 1) * NSTEPS) / SPLITS;
  const int nsteps = step1 - step0;   // 52 or 53

  const int t    = threadIdx.x;
  const int wid  = t >> 6;
  const int lane = t & 63;
  const int wr  = (wid >> 1) * 64;  // wave row offset in tile
  const int wc  = (wid & 1) * 64;   // wave col offset in tile
  const int l15 = lane & 15;
  const int l16 = lane >> 4;        // 0..3

  // --- A staging decomposition: 4 passes of 32 rows, 8 lanes x 16B per row
  const int arow = t >> 3;          // 0..31
  const int af4  = t & 7;           // fp32x4 chunk in row
  const int aswz = (arow >> 1) & 3; // invariant under row+32p
  const int aoff = ((af4 >> 1) ^ aswz) * 8 + (af4 & 1) * 4;  // ushort offset
  const float* __restrict__ xptr = X + (size_t)(m0 + arow) * K_DIM + step0 * BK + af4 * 4;

  // --- B gload_lds decomposition: wave w, call q covers rows w*32+q*16..+16
  const int brow0 = wid * 32 + (lane >> 2);          // rows for q=0 (q=1: +16)
  const int bch   = (lane & 3) ^ ((brow0 >> 1) & 3); // src chunk (swizzle inv.)
  const uint16_t* __restrict__ bsrc0 =
      Bt + (size_t)(n0 + brow0) * K_DIM + step0 * BK + bch * 8;
  const uint16_t* __restrict__ bsrc1 = bsrc0 + (size_t)16 * K_DIM;
  const int bdst0 = wid * 1024;     // ushort offset of wave's q=0 chunk
  const int bdst1 = bdst0 + 512;

  // --- frag read offsets (chunk swizzle is mf/nf-invariant)
  const int fchunk = ((l16 ^ ((l15 >> 1) & 3)) << 3);

  f32x4 acc[4][4] = {};
  f32x4 rA[4], rB[4];

  // ---- prologue ----
  // issue B(0)->buf0, B(1)->buf1; load A(0)->rA, A(1)->rB; pack A(0)->Al[0]
  gload16(bsrc0, &Bl[0][bdst0]);
  gload16(bsrc1, &Bl[0][bdst1]);
  if (1 < nsteps) {
    gload16(bsrc0 + BK, &Bl[1][bdst0]);
    gload16(bsrc1 + BK, &Bl[1][bdst1]);
  }
  __builtin_amdgcn_sched_barrier(0);
#pragma unroll
  for (int p = 0; p < 4; ++p)
    rA[p] = *reinterpret_cast<const f32x4*>(xptr + (size_t)p * 32 * K_DIM);
  if (1 < nsteps) {
#pragma unroll
    for (int p = 0; p < 4; ++p)
      rB[p] = *reinterpret_cast<const f32x4*>(xptr + (size_t)p * 32 * K_DIM + BK);
  }
#pragma unroll
  for (int p = 0; p < 4; ++p) {   // pack A(0) (compiler waits vmcnt(4): rA only)
    u32x2 w;
    w[0] = pack_bf16x2(rA[p][0], rA[p][1]);
    w[1] = pack_bf16x2(rA[p][2], rA[p][3]);
    *reinterpret_cast<u32x2*>(&Al[0][(arow + p * 32) * 32 + aoff]) = w;
  }
  asm volatile("s_waitcnt vmcnt(4) lgkmcnt(0)" ::: "memory");  // A(1) stays in flight
  __builtin_amdgcn_s_barrier();
  __builtin_amdgcn_sched_barrier(0);

  // ---- main loop, unrolled by 2 for static register sets ----
#define GEMM_STEP(I, RLOAD, RPACK)                                             \
  {                                                                            \
    const bool have2 = ((I) + 2 < nsteps);                                     \
    const bool have1 = ((I) + 1 < nsteps);                                     \
    if (have2) {                                                               \
      const int koff = ((I) + 2) * BK;                                         \
      uint16_t* bb = &Bl[((I) + 2) & 3][0];                                    \
      gload16(bsrc0 + koff, bb + bdst0);                                       \
      gload16(bsrc1 + koff, bb + bdst1);                                       \
      __builtin_amdgcn_sched_barrier(0);                                       \
      _Pragma("unroll")                                                        \
      for (int p = 0; p < 4; ++p)                                              \
        RLOAD[p] = *reinterpret_cast<const f32x4*>(                            \
            xptr + (size_t)p * 32 * K_DIM + koff);                             \
    }                                                                          \
    const uint16_t* __restrict__ Ar = &Al[(I) & 1][0];                         \
    const uint16_t* __restrict__ Br = &Bl[(I) & 3][0];                         \
    bf16x8 afr[4], bfr[4];                                                     \
    _Pragma("unroll")                                                          \
    for (int mf = 0; mf < 4; ++mf)                                             \
      afr[mf] = *reinterpret_cast<const bf16x8*>(                              \
          &Ar[(wr + mf * 16 + l15) * 32 + fchunk]);                            \
    _Pragma("unroll")                                                          \
    for (int nf = 0; nf < 4; ++nf)                                             \
      bfr[nf] = *reinterpret_cast<const bf16x8*>(                              \
          &Br[(wc + nf * 16 + l15) * 32 + fchunk]);                            \
    _Pragma("unroll")                                                          \
    for (int mf = 0; mf < 4; ++mf)                                             \
      _Pragma("unroll")                                                        \
      for (int nf = 0; nf < 4; ++nf)                                           \
        acc[mf][nf] = __builtin_amdgcn_mfma_f32_16x16x32_bf16(                 \
            afr[mf], bfr[nf], acc[mf][nf], 0, 0, 0);                           \
    if (have1) {                                                               \
      uint16_t* Aw = &Al[((I) + 1) & 1][0];                                    \
      _Pragma("unroll")                                                        \
      for (int p = 0; p < 4; ++p) {                                            \
        u32x2 w;                                                               \
        w[0] = pack_bf16x2(RPACK[p][0], RPACK[p][1]);                          \
        w[1] = pack_bf16x2(RPACK[p][2], RPACK[p][3]);                          \
        *reinterpret_cast<u32x2*>(&Aw[(arow + p * 32) * 32 + aoff]) = w;       \
      }                                                                        \
    }                                                                          \
    if (have2) {                                                               \
      asm volatile("s_waitcnt vmcnt(6) lgkmcnt(0)" ::: "memory");              \
    } else {                                                                   \
      asm volatile("s_waitcnt vmcnt(0) lgkmcnt(0)" ::: "memory");              \
    }                                                                          \
    __builtin_amdgcn_s_barrier();                                              \
    __builtin_amdgcn_sched_barrier(0);                                         \
  }

  for (int i = 0; i < nsteps; i += 2) {
    GEMM_STEP(i, rA, rB);
    if (i + 1 < nsteps) GEMM_STEP(i + 1, rB, rA);
  }
#undef GEMM_STEP

  // epilogue: scaled atomic accumulation (C/D: col = lane&15, row = (lane>>4)*4 + j)
  const float scale = 1.0f / (float)K_DIM;
#pragma unroll
  for (int mf = 0; mf < 4; ++mf) {
#pragma unroll
    for (int nf = 0; nf < 4; ++nf) {
      const int row = m0 + wr + mf * 16 + l16 * 4;
      const int col = n0 + wc + nf * 16 + l15;
#pragma unroll
      for (int j = 0; j < 4; ++j)
        atomicAdd(&out[(size_t)(row + j) * N_DIM + col], acc[mf][nf][j] * scale);
    }
  }
}

// ---------------------------------------------------------------------------
extern "C" void kernel_launch(void* const* d_in, const int* in_sizes, int n_in,
                              void* d_out, int out_size, void* d_ws, size_t ws_size,
                              hipStream_t stream) {
  (void)in_sizes; (void)n_in; (void)out_size; (void)ws_size;
  const float* x    = (const float*)d_in[0];
  const float* emb  = (const float*)d_in[1];
  const float* bias = (const float*)d_in[2];
  float*    out = (float*)d_out;
  uint16_t* bt  = (uint16_t*)d_ws;   // 512*20000*2 = 20.48 MB

  bt_transpose_kernel<<<dim3(K_DIM / 32, N_DIM / 64), 256, 0, stream>>>(emb, bt);
  init_out_kernel<<<(M_DIM * N_DIM) / 256, 256, 0, stream>>>(bias, out);
  gemm_split_kernel<<<GRID, GEMM_THREADS, 0, stream>>>(x, bt, out);
}